// Round 10
// baseline (240.247 us; speedup 1.0000x reference)
//
#include <hip/hip_runtime.h>

// Sparsemax over last axis of (16, 2048, 1024) fp32.
// One wave per row; Newton/Michelot from tau0 = max-1; DPP reductions.
//
// R10: async-pipeline experiment. R1/R8/R9 all pin at ~80us / 2.45 TB/s with
// idle VALU -> latency-bound with bursty per-wave load windows (4KB in flight,
// drained to 0 before each compute). Fix: global_load_lds double-buffer —
// each wave stages row t+1 into LDS (fire-and-forget DMA, no VGPRs) while
// computing row t from LDS; counted vmcnt(4/8) so staging + stores stay in
// flight across compute. 1024 blocks x 32KB LDS = 4 blocks/CU, all resident,
// ~64KB/CU continuously in flight. No barriers (each wave owns its row+slice).

typedef float f32x4 __attribute__((ext_vector_type(4)));

constexpr int N      = 1024;
constexpr int ROWS   = 16 * 2048;      // 32768
constexpr int NBLK   = 1024;           // 4 blocks/CU, fully resident, no tail
constexpr int RPB    = ROWS / NBLK;    // 32 rows per block
constexpr int NBATCH = RPB / 4;        // 8 batches (4 rows per batch, 1/wave)

template <int CTRL, int RM>
__device__ __forceinline__ float dpp_mov(float oldv, float src) {
    return __int_as_float(__builtin_amdgcn_update_dpp(
        __float_as_int(oldv), __float_as_int(src), CTRL, RM, 0xf, false));
}

// row_shr 1/2/4/8 (per-16 inclusive scan) + row_bcast:15 (rows 1,3) +
// row_bcast:31 (rows 2,3); total lands in lane 63; readlane broadcasts.
__device__ __forceinline__ float wave_max_dpp(float v) {
    v = fmaxf(v, dpp_mov<0x111, 0xf>(v, v));
    v = fmaxf(v, dpp_mov<0x112, 0xf>(v, v));
    v = fmaxf(v, dpp_mov<0x114, 0xf>(v, v));
    v = fmaxf(v, dpp_mov<0x118, 0xf>(v, v));
    v = fmaxf(v, dpp_mov<0x142, 0xa>(v, v));
    v = fmaxf(v, dpp_mov<0x143, 0xc>(v, v));
    return __int_as_float(__builtin_amdgcn_readlane(__float_as_int(v), 63));
}

__device__ __forceinline__ float wave_sum_dpp(float v) {
    v += dpp_mov<0x111, 0xf>(0.0f, v);
    v += dpp_mov<0x112, 0xf>(0.0f, v);
    v += dpp_mov<0x114, 0xf>(0.0f, v);
    v += dpp_mov<0x118, 0xf>(0.0f, v);
    v += dpp_mov<0x142, 0xa>(0.0f, v);
    v += dpp_mov<0x143, 0xc>(0.0f, v);
    return __int_as_float(__builtin_amdgcn_readlane(__float_as_int(v), 63));
}

__global__ __launch_bounds__(256) void sparsemax_kernel(const float* __restrict__ x,
                                                        float* __restrict__ out) {
    __shared__ float lds[2][4][N];     // 32 KiB: double-buffer x 4 waves x row

    const int wid  = threadIdx.x >> 6;
    const int lane = threadIdx.x & 63;

    f32x4* __restrict__ ov = reinterpret_cast<f32x4*>(out);

    // Stage batch t's row for this wave into LDS buffer bf.
    // Each inst: 64 lanes x 16B = 1KB; LDS dst wave-uniform, lanes land at
    // dst + lane*16 (linear layout == natural row order).
    auto stage = [&](int t, int bf) {
        const long long row = (long long)blockIdx.x * RPB + t * 4 + wid;
        const float* gs = x + row * N + lane * 4;
        float* ld = &lds[bf][wid][0];
        #pragma unroll
        for (int j = 0; j < 4; ++j) {
            __builtin_amdgcn_global_load_lds(
                (const __attribute__((address_space(1))) void*)(gs + j * 256),
                (__attribute__((address_space(3))) void*)(ld + j * 256),
                16, 0, 0);
        }
    };

    stage(0, 0);

    #pragma unroll
    for (int t = 0; t < NBATCH; ++t) {
        if (t + 1 < NBATCH) stage(t + 1, (t + 1) & 1);

        // Wait only for batch t's 4 staging ops (oldest in flight); keep
        // stage(t+1) [4 ops] and stores(t-1) [4 ops] outstanding.
        if (t == 0 || t == NBATCH - 1) {
            asm volatile("s_waitcnt vmcnt(4)" ::: "memory");
        } else {
            asm volatile("s_waitcnt vmcnt(8)" ::: "memory");
        }
        __builtin_amdgcn_sched_barrier(0);

        // Row from LDS: z[4j+c] = row[256j + 4*lane + c].
        const f32x4* lp = reinterpret_cast<const f32x4*>(&lds[t & 1][wid][0]);
        float z[16];
        #pragma unroll
        for (int j = 0; j < 4; ++j) {
            f32x4 v = lp[lane + 64 * j];
            z[4 * j + 0] = v.x; z[4 * j + 1] = v.y;
            z[4 * j + 2] = v.z; z[4 * j + 3] = v.w;
        }

        // Per-lane max tree, then DPP wave max.
        float m;
        {
            float a0 = fmaxf(z[0], z[1]),  a1 = fmaxf(z[2], z[3]);
            float a2 = fmaxf(z[4], z[5]),  a3 = fmaxf(z[6], z[7]);
            float a4 = fmaxf(z[8], z[9]),  a5 = fmaxf(z[10], z[11]);
            float a6 = fmaxf(z[12], z[13]), a7 = fmaxf(z[14], z[15]);
            m = fmaxf(fmaxf(fmaxf(a0, a1), fmaxf(a2, a3)),
                      fmaxf(fmaxf(a4, a5), fmaxf(a6, a7)));
        }
        m = wave_max_dpp(m);

        // Michelot/Newton from tau0 = max-1 (tau* >= max-1 always).
        // Nested shrinking active sets; stable cardinality => exact tau.
        float tau   = m - 1.0f;
        int   kprev = N + 1;
        for (;;) {
            float s[16];
            int   lc = 0;
            #pragma unroll
            for (int i = 0; i < 16; ++i) {
                const bool p = z[i] > tau;
                s[i] = p ? z[i] : 0.0f;
                lc += (int)__builtin_popcountll(__ballot(p));
            }
            float t0 = (s[0] + s[1]) + (s[2] + s[3]);
            float t1 = (s[4] + s[5]) + (s[6] + s[7]);
            float t2 = (s[8] + s[9]) + (s[10] + s[11]);
            float t3 = (s[12] + s[13]) + (s[14] + s[15]);
            float ls = wave_sum_dpp((t0 + t1) + (t2 + t3));
            if (lc >= kprev) break;
            kprev = lc;
            tau = (ls - 1.0f) * __builtin_amdgcn_rcpf((float)lc);
        }

        // Coalesced stores (kept in flight across next batch via counted vmcnt).
        const long long row = (long long)blockIdx.x * RPB + t * 4 + wid;
        const long long ob  = row * 256 + lane;
        #pragma unroll
        for (int j = 0; j < 4; ++j) {
            f32x4 o4;
            o4.x = fmaxf(z[4 * j + 0] - tau, 0.f);
            o4.y = fmaxf(z[4 * j + 1] - tau, 0.f);
            o4.z = fmaxf(z[4 * j + 2] - tau, 0.f);
            o4.w = fmaxf(z[4 * j + 3] - tau, 0.f);
            ov[ob + 64 * j] = o4;
        }
    }
}

extern "C" void kernel_launch(void* const* d_in, const int* in_sizes, int n_in,
                              void* d_out, int out_size, void* d_ws, size_t ws_size,
                              hipStream_t stream) {
    const float* x   = (const float*)d_in[0];
    float*       out = (float*)d_out;
    hipLaunchKernelGGL(sparsemax_kernel, dim3(NBLK), dim3(256), 0, stream, x, out);
}